// Round 1
// baseline (391.363 us; speedup 1.0000x reference)
//
#include <hip/hip_runtime.h>
#include <stdint.h>
#include <stddef.h>

#define NB 32
#define CD 512
#define KC 1024
#define PBATCH 1024
#define NR 32768  // NB*PBATCH

typedef __attribute__((ext_vector_type(8))) short short8_t;
typedef __attribute__((ext_vector_type(8))) __bf16 bf16x8_t;
typedef __attribute__((ext_vector_type(4))) float f32x4_t;

__device__ __forceinline__ uint16_t f2bf(float f) {
  uint32_t u = __float_as_uint(f);
  u += 0x7fffu + ((u >> 16) & 1u);
  return (uint16_t)(u >> 16);
}
__device__ __forceinline__ float bf2f(uint16_t h) {
  return __uint_as_float(((uint32_t)h) << 16);
}
__device__ __forceinline__ float soft_sign(float x) {
  // matches 2*sigmoid(100x)-1 op-for-op
  float e = expf(-100.0f * x);
  float s = 1.0f / (1.0f + e);
  return 2.0f * s - 1.0f;
}

// ---------------- codebook -> bf16, pre-swizzled [k][c] ----------------
__global__ __launch_bounds__(256) void k_prep_cb(const float* __restrict__ cb,
                                                 uint16_t* __restrict__ cbb) {
  int i = blockIdx.x * 256 + threadIdx.x;  // 524288
  int k = i >> 9, c = i & 511;
  int cc = c & 63;
  int swz = ((((cc >> 3) ^ (k & 7)) << 3) | (cc & 7));
  cbb[((size_t)k << 9) + (c & ~63) + swz] = f2bf(cb[i]);
}

// ---------------- codebook sign bits, transposed pack[c/32][k] ----------------
__global__ __launch_bounds__(256) void k_pack(const float* __restrict__ cb,
                                              uint32_t* __restrict__ pack) {
  int i = blockIdx.x * 256 + threadIdx.x;  // 524288
  int k = i >> 9, c = i & 511;
  unsigned long long m = __ballot(cb[i] > 0.0f);
  int lane = threadIdx.x & 63;
  if ((lane & 31) == 0) pack[((c >> 5) << 10) + k] = (uint32_t)(m >> (lane & 32));
}

// ---------------- x -> xs -> (hi,lo) bf16, transposed to [n][c], pre-swizzled ----------------
__global__ __launch_bounds__(256) void k_prep_x(const float* __restrict__ x,
                                                uint16_t* __restrict__ xhi,
                                                uint16_t* __restrict__ xlo) {
  __shared__ float lxs[64][129];  // +1 pad: transposed read 2-way banks (free)
  int blk = blockIdx.x;           // 32 b * 8 cchunk * 8 pchunk = 2048
  int b = blk >> 6;
  int c0 = ((blk >> 3) & 7) << 6;
  int p0 = (blk & 7) << 7;
  int tid = threadIdx.x;
  const float* xb = x + ((size_t)b * CD * PBATCH);
  for (int it = 0; it < 32; ++it) {
    int f = it * 256 + tid;
    int cr = f >> 7, pc = f & 127;
    lxs[cr][pc] = soft_sign(xb[(size_t)(c0 + cr) * PBATCH + p0 + pc]);
  }
  __syncthreads();
  for (int it = 0; it < 32; ++it) {
    int f = it * 256 + tid;
    int pr = f >> 6, cc = f & 63;
    float xs = lxs[cc][pr];
    uint16_t h = f2bf(xs);
    uint16_t l = f2bf(xs - bf2f(h));
    int n = b * PBATCH + p0 + pr;
    int swz = ((((cc >> 3) ^ (n & 7)) << 3) | (cc & 7));
    size_t off = ((size_t)n << 9) + c0 + swz;
    xhi[off] = h;
    xlo[off] = l;
  }
}

// ---------------- s[n] = fp32(sum_c xs^2 (f64 acc)) + 512 ----------------
__global__ __launch_bounds__(256) void k_rownorm(const float* __restrict__ x,
                                                 float* __restrict__ srow) {
  int b = blockIdx.x >> 2;  // grid 128
  int p = ((blockIdx.x & 3) << 8) + threadIdx.x;
  const float* xb = x + ((size_t)b * CD * PBATCH) + p;
  double acc = 0.0;
  for (int c = 0; c < CD; ++c) {
    float xs = soft_sign(xb[(size_t)c * PBATCH]);
    float sq = xs * xs;  // square rounded to fp32 like numpy
    acc += (double)sq;
  }
  srow[b * PBATCH + p] = (float)acc + 512.0f;
}

__device__ __forceinline__ void gl_lds16(const uint16_t* g, uint16_t* l) {
  __builtin_amdgcn_global_load_lds((const uint32_t*)g, (uint32_t*)l, 16, 0, 0);
}

// ---------------- GEMM (D^T[k][p] = CB x Xs^T) + running argmin of d ----------------
// grid 512 = 32 b x 8 p-tiles x 2 k-halves; 256 thr = 4 waves (2x2);
// tile: 128 k x 128 p, BK=64 c; reduction runs hi-pass then lo-pass (split bf16).
__global__ __launch_bounds__(256, 2) void k_gemm(
    const uint16_t* __restrict__ cbb, const uint16_t* __restrict__ xhi,
    const uint16_t* __restrict__ xlo, const float* __restrict__ srow,
    float* __restrict__ dtmp, int* __restrict__ ktmp) {
  __shared__ alignas(16) uint8_t smem[65536];
  uint16_t* lsa = (uint16_t*)smem;          // A: CB tile  [2][128*64]
  uint16_t* lsb = (uint16_t*)smem + 16384;  // B: Xs tile  [2][128*64]

  int blk = blockIdx.x;
  int kh = blk & 1;
  int pt = (blk >> 1) & 7;
  int b = blk >> 4;
  int tid = threadIdx.x;
  int lane = tid & 63, wid = tid >> 6;
  int wr = wid >> 1, wc = wid & 1;
  int g = lane >> 4, r15 = lane & 15;

  int n0 = b * PBATCH + (pt << 7);
  const uint16_t* xh = xhi + ((size_t)n0 << 9);
  const uint16_t* xl = xlo + ((size_t)n0 << 9);
  const uint16_t* cbk = cbb + (((size_t)kh << 9) << 9);  // kh*512 rows

  float s_p[4];
#pragma unroll
  for (int ac = 0; ac < 4; ++ac) s_p[ac] = srow[n0 + (wc << 6) + (ac << 4) + r15];

  float best_d[4];
  int best_k[4];
#pragma unroll
  for (int ac = 0; ac < 4; ++ac) { best_d[ac] = 3.4e38f; best_k[ac] = 0; }

  // step in [0,64): kt = step>>4, pass = (step>>3)&1 (hi/lo), c0 = (step&7)*64
  auto stage = [&](int buf, int step) {
    int kt = step >> 4;
    const uint16_t* bs = ((step >> 3) & 1) ? xl : xh;
    int c0 = (step & 7) << 6;
    const uint16_t* as = cbk + (((size_t)kt << 7) << 9) + c0;
    bs += c0;
    uint16_t* la = lsa + buf * 8192;
    uint16_t* lb = lsb + buf * 8192;
#pragma unroll
    for (int i = 0; i < 4; ++i) {
      int e = (wid << 11) + (i << 9) + (lane << 3);
      int row = e >> 6, col = e & 63;
      size_t go = ((size_t)row << 9) + col;
      int lo_ = (wid << 11) + (i << 9);  // wave-uniform LDS base
      gl_lds16(as + go, la + lo_);
      gl_lds16(bs + go, lb + lo_);
    }
  };

  f32x4_t acc[4][4];

  stage(0, 0);
  asm volatile("s_waitcnt vmcnt(0)" ::: "memory");
  __builtin_amdgcn_s_barrier();
  asm volatile("" ::: "memory");

  int cur = 0;
  for (int step = 0; step < 64; ++step) {
    if ((step & 15) == 0) {
#pragma unroll
      for (int i = 0; i < 4; ++i)
#pragma unroll
        for (int j = 0; j < 4; ++j) acc[i][j] = (f32x4_t){0.f, 0.f, 0.f, 0.f};
    }
    if (step + 1 < 64) stage(cur ^ 1, step + 1);

    uint16_t* la = lsa + cur * 8192;
    uint16_t* lb = lsb + cur * 8192;
#pragma unroll
    for (int cs = 0; cs < 2; ++cs) {
      bf16x8_t af[4], bfr[4];
#pragma unroll
      for (int ar = 0; ar < 4; ++ar) {
        int row = (wr << 6) + (ar << 4) + r15;
        int off = (row << 6) + ((((cs << 2) | g) ^ (row & 7)) << 3);
        af[ar] = __builtin_bit_cast(bf16x8_t, *(const short8_t*)(la + off));
      }
#pragma unroll
      for (int ac = 0; ac < 4; ++ac) {
        int row = (wc << 6) + (ac << 4) + r15;
        int off = (row << 6) + ((((cs << 2) | g) ^ (row & 7)) << 3);
        bfr[ac] = __builtin_bit_cast(bf16x8_t, *(const short8_t*)(lb + off));
      }
#pragma unroll
      for (int ar = 0; ar < 4; ++ar)
#pragma unroll
        for (int ac = 0; ac < 4; ++ac)
          acc[ar][ac] =
              __builtin_amdgcn_mfma_f32_16x16x32_bf16(af[ar], bfr[ac], acc[ar][ac], 0, 0, 0);
    }

    if ((step & 15) == 15) {  // end of a 128-row k-tile: fold into running argmin
      int kbase = (kh << 9) + ((step >> 4) << 7) + (wr << 6);
#pragma unroll
      for (int ar = 0; ar < 4; ++ar)
#pragma unroll
        for (int ac = 0; ac < 4; ++ac)
#pragma unroll
          for (int rg = 0; rg < 4; ++rg) {
            float d = fmaf(-2.0f, acc[ar][ac][rg], s_p[ac]);  // == fl(s - 2*dot)
            int kk = kbase + (ar << 4) + (g << 2) + rg;
            bool better = (d < best_d[ac]) || (d == best_d[ac] && kk < best_k[ac]);
            if (better) { best_d[ac] = d; best_k[ac] = kk; }
          }
    }

    asm volatile("s_waitcnt vmcnt(0)" ::: "memory");
    __builtin_amdgcn_s_barrier();
    asm volatile("" ::: "memory");
    cur ^= 1;
  }

  // reduce across lane groups sharing the same p (lex order: min d, then min k)
  float myd = 0.f;
  int myk = 0;
#pragma unroll
  for (int ac = 0; ac < 4; ++ac) {
    float d = best_d[ac];
    int k = best_k[ac];
#pragma unroll
    for (int m = 16; m <= 32; m <<= 1) {
      float od = __shfl_xor(d, m);
      int ok = __shfl_xor(k, m);
      if (od < d || (od == d && ok < k)) { d = od; k = ok; }
    }
    if (g == ac) { myd = d; myk = k; }
  }
  float* sd = (float*)smem;         // reuse LDS (buffers dead)
  int* sk = (int*)(smem + 1024);
  __syncthreads();
  int plocal = (wc << 6) + (g << 4) + r15;
  sd[wr * 128 + plocal] = myd;
  sk[wr * 128 + plocal] = myk;
  __syncthreads();
  if (tid < 128) {
    float d0 = sd[tid]; int k0 = sk[tid];
    float d1 = sd[128 + tid]; int k1 = sk[128 + tid];
    if (d1 < d0 || (d1 == d0 && k1 < k0)) { d0 = d1; k0 = k1; }
    int n = n0 + tid;
    dtmp[(size_t)kh * NR + n] = d0;
    ktmp[(size_t)kh * NR + n] = k0;
  }
}

// ---------------- merge the 2 k-halves, histogram ----------------
__global__ __launch_bounds__(256) void k_merge(const float* __restrict__ dtmp,
                                               const int* __restrict__ ktmp,
                                               int* __restrict__ idx,
                                               int* __restrict__ counts) {
  int n = blockIdx.x * 256 + threadIdx.x;  // grid 128
  float d0 = dtmp[n]; int k0 = ktmp[n];
  float d1 = dtmp[NR + n]; int k1 = ktmp[NR + n];
  int k = (d1 < d0 || (d1 == d0 && k1 < k0)) ? k1 : k0;
  idx[n] = k;
  atomicAdd(&counts[k], 1);
}

// ---------------- perplexity scalars ----------------
__global__ __launch_bounds__(256) void k_perp(const int* __restrict__ counts,
                                              float* __restrict__ out2) {
  int tid = threadIdx.x;
  float local = 0.0f;
  for (int i = tid; i < KC; i += 256) {
    int c = counts[i];
    if (c > 0) {
      float p = (float)c * (1.0f / 32768.0f);
      local += p * logf(p);
    }
  }
#pragma unroll
  for (int m = 1; m < 64; m <<= 1) local += __shfl_xor(local, m);
  __shared__ float wsum[4];
  if ((tid & 63) == 0) wsum[tid >> 6] = local;
  __syncthreads();
  if (tid == 0) {
    float entropy = -(wsum[0] + wsum[1] + wsum[2] + wsum[3]);
    float pl = 1.0f / expf(entropy);
    out2[0] = pl;
    out2[1] = 0.25f * pl;
  }
}

// ---------------- gather via bit-packed codebook in LDS ----------------
__global__ __launch_bounds__(256) void k_gather(const int* __restrict__ idx,
                                                const uint32_t* __restrict__ pack,
                                                float* __restrict__ out) {
  __shared__ uint32_t lp[16384];  // 64 KB sign table
  int tid = threadIdx.x;
  for (int i = 0; i < 64; ++i) lp[i * 256 + tid] = pack[i * 256 + tid];
  __syncthreads();
  int base = blockIdx.x * 2048;  // grid 2048, 4.19M float4 total
  for (int it = 0; it < 8; ++it) {
    int t = base + it * 256 + tid;
    int pq = t & 255;
    int c = (t >> 8) & 511;
    int b = t >> 17;
    int4 iv = reinterpret_cast<const int4*>(idx)[(b << 8) + pq];
    int cw = c >> 5, cbit = c & 31;
    float4 r;
    r.x = ((lp[(cw << 10) + iv.x] >> cbit) & 1) ? 1.0f : -1.0f;
    r.y = ((lp[(cw << 10) + iv.y] >> cbit) & 1) ? 1.0f : -1.0f;
    r.z = ((lp[(cw << 10) + iv.z] >> cbit) & 1) ? 1.0f : -1.0f;
    r.w = ((lp[(cw << 10) + iv.w] >> cbit) & 1) ? 1.0f : -1.0f;
    reinterpret_cast<float4*>(out)[t] = r;
  }
}

extern "C" void kernel_launch(void* const* d_in, const int* in_sizes, int n_in,
                              void* d_out, int out_size, void* d_ws, size_t ws_size,
                              hipStream_t stream) {
  const float* x = (const float*)d_in[0];
  const float* cb = (const float*)d_in[1];
  float* out = (float*)d_out;

  uint8_t* ws = (uint8_t*)d_ws;
  uint16_t* cbb = (uint16_t*)ws;                                     // 1,048,576
  float* srow = (float*)(ws + 1048576);                              //   131,072
  float* dtmp = (float*)(ws + 1048576 + 131072);                     //   262,144
  int* ktmp = (int*)(ws + 1048576 + 131072 + 262144);                //   262,144
  int* idx = (int*)(ws + 1048576 + 131072 + 262144 + 262144);        //   131,072
  int* counts = (int*)(ws + 1048576 + 131072 + 262144 + 262144 + 131072);  // 4,096
  uint32_t* pack = (uint32_t*)(ws + 1048576 + 131072 + 262144 + 262144 + 131072 + 4096);  // 65,536
  size_t small_end = 1048576 + 131072 + 262144 + 262144 + 131072 + 4096 + 65536;

  uint16_t *xhi, *xlo;
  if (ws_size >= small_end + (size_t)NR * CD * 2 * 2) {
    xhi = (uint16_t*)(ws + small_end);
    xlo = xhi + (size_t)NR * CD;
  } else {
    // fallback: use d_out as scratch for the bf16 split (dead before k_gather writes)
    xhi = (uint16_t*)d_out;
    xlo = xhi + (size_t)NR * CD;
  }

  k_prep_cb<<<2048, 256, 0, stream>>>(cb, cbb);
  k_pack<<<2048, 256, 0, stream>>>(cb, pack);
  k_prep_x<<<2048, 256, 0, stream>>>(x, xhi, xlo);
  k_rownorm<<<128, 256, 0, stream>>>(x, srow);
  hipMemsetAsync(counts, 0, 4096, stream);
  k_gemm<<<512, 256, 0, stream>>>(cbb, xhi, xlo, srow, dtmp, ktmp);
  k_merge<<<128, 256, 0, stream>>>(dtmp, ktmp, idx, counts);
  k_perp<<<1, 256, 0, stream>>>(counts, out + 16777216);
  k_gather<<<2048, 256, 0, stream>>>(idx, pack, out);
}

// Round 3
// 225.258 us; speedup vs baseline: 1.7374x; 1.7374x over previous
//
#include <hip/hip_runtime.h>
#include <stdint.h>
#include <stddef.h>

#define CD 512
#define KC 1024
#define NR 32768  // total rows (32*1024)

typedef __attribute__((ext_vector_type(8))) short short8_t;
typedef __attribute__((ext_vector_type(8))) __bf16 bf16x8_t;
typedef __attribute__((ext_vector_type(4))) float f32x4_t;

__device__ __forceinline__ uint16_t f2bf(float f) {
  uint32_t u = __float_as_uint(f);
  u += 0x7fffu + ((u >> 16) & 1u);
  return (uint16_t)(u >> 16);
}
__device__ __forceinline__ float bf2f(uint16_t h) {
  return __uint_as_float(((uint32_t)h) << 16);
}
__device__ __forceinline__ float soft_sign(float x) {
  // 2*sigmoid(100x)-1 ; fast path (rel err ~1e-7 -> dot shift ~2e-6 << margin)
  float e = __expf(-100.0f * x);
  float s = __builtin_amdgcn_rcpf(1.0f + e);
  return fmaf(2.0f, s, -1.0f);
}

// ---- codebook -> bf16 pre-swizzled [k][c]  +  sign-bit pack[c/32][k] ----
__global__ __launch_bounds__(256) void k_cb(const float* __restrict__ cb,
                                            uint16_t* __restrict__ cbb,
                                            uint32_t* __restrict__ pack) {
  int i = blockIdx.x * 256 + threadIdx.x;  // 524288
  float v = cb[i];
  int k = i >> 9, c = i & 511;
  int cc = c & 63;
  int swz = ((((cc >> 3) ^ (k & 7)) << 3) | (cc & 7));
  cbb[((size_t)k << 9) + (c & ~63) + swz] = f2bf(v);
  unsigned long long m = __ballot(v > 0.0f);
  int lane = threadIdx.x & 63;
  if ((lane & 31) == 0) pack[((c >> 5) << 10) + k] = (uint32_t)(m >> (lane & 32));
}

// ---- x -> xs -> (hi,lo) bf16 transposed [n][c] pre-swizzled + f64 row norms ----
// grid 256 = 32 b * 8 p-chunks(128); 256 thr.
__global__ __launch_bounds__(256) void k_prep(const float* __restrict__ x,
                                              uint16_t* __restrict__ xhi,
                                              uint16_t* __restrict__ xlo,
                                              float* __restrict__ srow) {
  __shared__ float lxs[64][129];
  int blk = blockIdx.x;
  int b = blk >> 3;
  int p0 = (blk & 7) << 7;
  int tid = threadIdx.x;
  int n0 = (b << 10) + p0;
  int oc = tid & 7, nr = tid >> 3;  // write-phase ids: nr in [0,32)
  double sum[4] = {0.0, 0.0, 0.0, 0.0};
  const float* xb = x + (((size_t)b) << 19) + p0;  // b*512*1024

  for (int ch = 0; ch < 8; ++ch) {
    int c0 = ch << 6;
#pragma unroll
    for (int it = 0; it < 8; ++it) {
      int cr = (it << 3) + (tid >> 5);
      int q = tid & 31;
      const float4 v =
          *reinterpret_cast<const float4*>(xb + (((size_t)(c0 + cr)) << 10) + (q << 2));
      lxs[cr][(q << 2) + 0] = soft_sign(v.x);
      lxs[cr][(q << 2) + 1] = soft_sign(v.y);
      lxs[cr][(q << 2) + 2] = soft_sign(v.z);
      lxs[cr][(q << 2) + 3] = soft_sign(v.w);
    }
    __syncthreads();
#pragma unroll
    for (int it = 0; it < 4; ++it) {
      int r = (it << 5) + nr;
      int n = n0 + r;
      short8_t h8, l8;
      double ls = 0.0;
#pragma unroll
      for (int j = 0; j < 8; ++j) {
        float xs = lxs[(oc << 3) + j][r];
        uint16_t h = f2bf(xs);
        uint16_t l = f2bf(xs - bf2f(h));
        h8[j] = (short)h;
        l8[j] = (short)l;
        float sq = xs * xs;
        ls += (double)sq;
      }
      sum[it] += ls;
      size_t off = (((size_t)n) << 9) + (size_t)c0 + (size_t)(((oc ^ (n & 7)) << 3));
      *reinterpret_cast<short8_t*>(xhi + off) = h8;
      *reinterpret_cast<short8_t*>(xlo + off) = l8;
    }
    __syncthreads();
  }
#pragma unroll
  for (int it = 0; it < 4; ++it) {
    double s = sum[it];
#pragma unroll
    for (int m = 1; m < 8; m <<= 1) s += __shfl_xor(s, m);
    if (oc == 0) srow[n0 + (it << 5) + nr] = (float)s + 512.0f;
  }
}

__device__ __forceinline__ void gl_lds16(const uint16_t* g, uint16_t* l) {
  __builtin_amdgcn_global_load_lds((const uint32_t*)g, (uint32_t*)l, 16, 0, 0);
}

// ---------------- GEMM + argmin: block = 64 p-rows, full K=1024 ----------------
// 512 thr = 8 waves (4 k-grp x 2 p-grp), 2 waves/SIMD. LDS: A dbuf 2x16KB + B 128KB.
// steps: kt 0..7 (128 codes) x cc 0..7 (64 c); hi+lo accumulate into the same acc.
__global__ __launch_bounds__(512, 1) void k_gemm(
    const uint16_t* __restrict__ cbb, const uint16_t* __restrict__ xhi,
    const uint16_t* __restrict__ xlo, const float* __restrict__ srow,
    int* __restrict__ idx, int* __restrict__ counts) {
  extern __shared__ uint8_t smem[];
  uint16_t* lds = (uint16_t*)smem;  // element-indexed

  int blk = blockIdx.x;  // 512 blocks
  int tid = threadIdx.x;
  int lane = tid & 63, wid = tid >> 6;
  int kg = wid >> 1, pg = wid & 1;
  int g = lane >> 4, r15 = lane & 15;
  int n0 = blk << 6;

  float s_p[2];
#pragma unroll
  for (int ac = 0; ac < 2; ++ac) s_p[ac] = srow[n0 + (pg << 5) + (ac << 4) + r15];

  float best_d[2];
  int best_k[2];
#pragma unroll
  for (int ac = 0; ac < 2; ++ac) { best_d[ac] = 3.4e38f; best_k[ac] = 0; }

  // stage A chunk (kt,cc): 128 k-rows x 64 c -> lds[buf*8192 .. +8192)
  auto stageA = [&](int buf, int kt, int cc) {
    const uint16_t* base = cbb + ((size_t)(cc << 6)) + ((lane & 7) << 3);
    uint16_t* lb = lds + (buf << 13);
#pragma unroll
    for (int i = 0; i < 2; ++i) {
      int r = (wid << 1) + i;  // 0..15, 8 rows each
      gl_lds16(base + (((size_t)((kt << 7) + (r << 3) + (lane >> 3))) << 9), lb + (r << 9));
    }
  };
  // stage B chunk cc (both passes): 64 p-rows x 64 c x {hi,lo}
  auto stageB = [&](int cc) {
#pragma unroll
    for (int t = 0; t < 2; ++t) {
      const uint16_t* src = t ? xlo : xhi;
      gl_lds16(src + (((size_t)(n0 + (wid << 3) + (lane >> 3))) << 9) + (cc << 6) +
                   ((lane & 7) << 3),
               lds + 16384 + (t << 15) + (cc << 12) + (wid << 9));
    }
  };

  f32x4_t acc[2][2];

  stageA(0, 0, 0);
  stageB(0);
  asm volatile("s_waitcnt vmcnt(0)" ::: "memory");
  __builtin_amdgcn_s_barrier();
  asm volatile("" ::: "memory");

  int cur = 0;
  for (int step = 0; step < 64; ++step) {
    int kt = step >> 3, cc = step & 7;
    if (cc == 0) {
#pragma unroll
      for (int i = 0; i < 2; ++i)
#pragma unroll
        for (int j = 0; j < 2; ++j) acc[i][j] = (f32x4_t){0.f, 0.f, 0.f, 0.f};
    }
    if (step < 7) stageB(step + 1);  // JIT B fill during ktile 0
    if (step < 63) {
      int ns = step + 1;
      stageA(cur ^ 1, ns >> 3, ns & 7);
    }

    const uint16_t* Acur = lds + (cur << 13);
    const uint16_t* Bc = lds + 16384 + (cc << 12);
#pragma unroll
    for (int cs = 0; cs < 2; ++cs) {
      bf16x8_t af[2], bh[2], bl[2];
#pragma unroll
      for (int ar = 0; ar < 2; ++ar) {
        int row = (kg << 5) + (ar << 4) + r15;
        int off = (row << 6) + (((((cs << 2) | g)) ^ (row & 7)) << 3);
        af[ar] = __builtin_bit_cast(bf16x8_t, *(const short8_t*)(Acur + off));
      }
#pragma unroll
      for (int ac = 0; ac < 2; ++ac) {
        int row = (pg << 5) + (ac << 4) + r15;
        int off = (row << 6) + ((((cs << 2) | g) ^ (row & 7)) << 3);
        bh[ac] = __builtin_bit_cast(bf16x8_t, *(const short8_t*)(Bc + off));
        bl[ac] = __builtin_bit_cast(bf16x8_t, *(const short8_t*)(Bc + 32768 + off));
      }
#pragma unroll
      for (int ar = 0; ar < 2; ++ar)
#pragma unroll
        for (int ac = 0; ac < 2; ++ac) {
          acc[ar][ac] =
              __builtin_amdgcn_mfma_f32_16x16x32_bf16(af[ar], bh[ac], acc[ar][ac], 0, 0, 0);
          acc[ar][ac] =
              __builtin_amdgcn_mfma_f32_16x16x32_bf16(af[ar], bl[ac], acc[ar][ac], 0, 0, 0);
        }
    }

    if (cc == 7) {  // fold 128-code tile into running argmin
      int kbase = (kt << 7) + (kg << 5);
#pragma unroll
      for (int ar = 0; ar < 2; ++ar)
#pragma unroll
        for (int ac = 0; ac < 2; ++ac)
#pragma unroll
          for (int rg = 0; rg < 4; ++rg) {
            float d = fmaf(-2.0f, acc[ar][ac][rg], s_p[ac]);  // fl(s - 2*dot)
            int kk = kbase + (ar << 4) + (g << 2) + rg;
            bool better = (d < best_d[ac]) || (d == best_d[ac] && kk < best_k[ac]);
            if (better) { best_d[ac] = d; best_k[ac] = kk; }
          }
    }

    asm volatile("s_waitcnt vmcnt(0)" ::: "memory");
    __builtin_amdgcn_s_barrier();
    asm volatile("" ::: "memory");
    cur ^= 1;
  }

  // merge g-groups (lex order: min d, then min k)
  float rd0, rd1;
  int rk0, rk1;
  {
    float d = best_d[0];
    int k = best_k[0];
#pragma unroll
    for (int m = 16; m <= 32; m <<= 1) {
      float od = __shfl_xor(d, m);
      int ok = __shfl_xor(k, m);
      if (od < d || (od == d && ok < k)) { d = od; k = ok; }
    }
    rd0 = d; rk0 = k;
  }
  {
    float d = best_d[1];
    int k = best_k[1];
#pragma unroll
    for (int m = 16; m <= 32; m <<= 1) {
      float od = __shfl_xor(d, m);
      int ok = __shfl_xor(k, m);
      if (od < d || (od == d && ok < k)) { d = od; k = ok; }
    }
    rd1 = d; rk1 = k;
  }
  float* sd = (float*)smem;
  int* sk = (int*)(smem + 1024);
  __syncthreads();
  if (g < 2) {
    float dv = (g == 0) ? rd0 : rd1;
    int kv = (g == 0) ? rk0 : rk1;
    sd[(kg << 6) + (pg << 5) + (g << 4) + r15] = dv;
    sk[(kg << 6) + (pg << 5) + (g << 4) + r15] = kv;
  }
  __syncthreads();
  if (tid < 64) {
    float d0 = sd[tid];
    int k0 = sk[tid];
#pragma unroll
    for (int kgi = 1; kgi < 4; ++kgi) {
      float d1 = sd[(kgi << 6) + tid];
      int k1 = sk[(kgi << 6) + tid];
      if (d1 < d0 || (d1 == d0 && k1 < k0)) { d0 = d1; k0 = k1; }
    }
    idx[n0 + tid] = k0;
    atomicAdd(&counts[k0], 1);
  }
}

// ---------------- perplexity scalars ----------------
__global__ __launch_bounds__(256) void k_perp(const int* __restrict__ counts,
                                              float* __restrict__ out2) {
  int tid = threadIdx.x;
  float local = 0.0f;
  for (int i = tid; i < KC; i += 256) {
    int c = counts[i];
    if (c > 0) {
      float p = (float)c * (1.0f / 32768.0f);
      local += p * logf(p);
    }
  }
#pragma unroll
  for (int m = 1; m < 64; m <<= 1) local += __shfl_xor(local, m);
  __shared__ float wsum[4];
  if ((tid & 63) == 0) wsum[tid >> 6] = local;
  __syncthreads();
  if (tid == 0) {
    float entropy = -(wsum[0] + wsum[1] + wsum[2] + wsum[3]);
    float pl = 1.0f / expf(entropy);
    out2[0] = pl;
    out2[1] = 0.25f * pl;
  }
}

// ---------------- gather via bit-packed codebook in LDS ----------------
__global__ __launch_bounds__(256) void k_gather(const int* __restrict__ idx,
                                                const uint32_t* __restrict__ pack,
                                                float* __restrict__ out) {
  __shared__ uint32_t lp[16384];  // 64 KB sign table
  int tid = threadIdx.x;
#pragma unroll
  for (int i = 0; i < 16; ++i)
    reinterpret_cast<uint4*>(lp)[i * 256 + tid] =
        reinterpret_cast<const uint4*>(pack)[i * 256 + tid];
  __syncthreads();
  int base = blockIdx.x * 2048;  // grid 2048
  for (int it = 0; it < 8; ++it) {
    int t = base + it * 256 + tid;
    int pq = t & 255;
    int c = (t >> 8) & 511;
    int b = t >> 17;
    int4 iv = reinterpret_cast<const int4*>(idx)[(b << 8) + pq];
    int cw = c >> 5, cbit = c & 31;
    float4 r;
    r.x = ((lp[(cw << 10) + iv.x] >> cbit) & 1) ? 1.0f : -1.0f;
    r.y = ((lp[(cw << 10) + iv.y] >> cbit) & 1) ? 1.0f : -1.0f;
    r.z = ((lp[(cw << 10) + iv.z] >> cbit) & 1) ? 1.0f : -1.0f;
    r.w = ((lp[(cw << 10) + iv.w] >> cbit) & 1) ? 1.0f : -1.0f;
    reinterpret_cast<float4*>(out)[t] = r;
  }
}

extern "C" void kernel_launch(void* const* d_in, const int* in_sizes, int n_in,
                              void* d_out, int out_size, void* d_ws, size_t ws_size,
                              hipStream_t stream) {
  (void)in_sizes; (void)n_in; (void)out_size;
  const float* x = (const float*)d_in[0];
  const float* cb = (const float*)d_in[1];
  float* out = (float*)d_out;

  uint8_t* ws = (uint8_t*)d_ws;
  uint16_t* cbb = (uint16_t*)ws;                         // [0, 1 MB)
  float* srow = (float*)(ws + 1048576);                  // 128 KB
  int* idx = (int*)(ws + 1048576 + 131072);              // 128 KB
  int* counts = (int*)(ws + 1048576 + 131072 + 131072);  // 4 KB
  uint32_t* pack = (uint32_t*)(ws + 1048576 + 131072 + 131072 + 4096);  // 64 KB
  size_t small_end = 1048576 + 131072 + 131072 + 4096 + 65536;

  uint16_t *xhi, *xlo;
  if (ws_size >= small_end + (size_t)NR * CD * 2 * 2) {
    xhi = (uint16_t*)(ws + small_end);
    xlo = xhi + (size_t)NR * CD;
  } else {
    // fallback: d_out as scratch for the bf16 split (dead before k_gather writes)
    xhi = (uint16_t*)d_out;
    xlo = xhi + (size_t)NR * CD;
  }

  hipFuncSetAttribute((const void*)k_gemm, hipFuncAttributeMaxDynamicSharedMemorySize,
                      163840);

  k_cb<<<2048, 256, 0, stream>>>(cb, cbb, pack);
  k_prep<<<256, 256, 0, stream>>>(x, xhi, xlo, srow);
  hipMemsetAsync(counts, 0, 4096, stream);
  k_gemm<<<512, 512, 163840, stream>>>(cbb, xhi, xlo, srow, idx, counts);
  k_perp<<<1, 256, 0, stream>>>(counts, out + 16777216);
  k_gather<<<2048, 256, 0, stream>>>(idx, pack, out);
}

// Round 4
// 213.892 us; speedup vs baseline: 1.8297x; 1.0531x over previous
//
#include <hip/hip_runtime.h>
#include <stdint.h>
#include <stddef.h>

#define CD 512
#define KC 1024
#define NR 32768  // total rows (32*1024)

typedef __attribute__((ext_vector_type(8))) short short8_t;
typedef __attribute__((ext_vector_type(8))) __bf16 bf16x8_t;
typedef __attribute__((ext_vector_type(4))) float f32x4_t;

__device__ __forceinline__ uint16_t f2bf(float f) {
  uint32_t u = __float_as_uint(f);
  u += 0x7fffu + ((u >> 16) & 1u);
  return (uint16_t)(u >> 16);
}
__device__ __forceinline__ float bf2f(uint16_t h) {
  return __uint_as_float(((uint32_t)h) << 16);
}
__device__ __forceinline__ float soft_sign(float x) {
  // 2*sigmoid(100x)-1 ; fast path (rel err ~1e-7 -> dot shift ~2e-6 << margin)
  float e = __expf(-100.0f * x);
  float s = __builtin_amdgcn_rcpf(1.0f + e);
  return fmaf(2.0f, s, -1.0f);
}

// ---- codebook -> bf16 plain [k][c]  +  sign-bit pack[c/32][k] ----
__global__ __launch_bounds__(256) void k_cb(const float* __restrict__ cb,
                                            uint16_t* __restrict__ cbb,
                                            uint32_t* __restrict__ pack) {
  int i = blockIdx.x * 256 + threadIdx.x;  // 524288
  float v = cb[i];
  cbb[i] = f2bf(v);
  int k = i >> 9, c = i & 511;
  unsigned long long m = __ballot(v > 0.0f);
  int lane = threadIdx.x & 63;
  if ((lane & 31) == 0) pack[((c >> 5) << 10) + k] = (uint32_t)(m >> (lane & 32));
}

__device__ __forceinline__ void gl_lds16(const uint16_t* g, uint16_t* l) {
  __builtin_amdgcn_global_load_lds((const uint32_t*)g, (uint32_t*)l, 16, 0, 0);
}

// ------------- fused prep + GEMM + argmin: block = 64 p-rows, full K -------------
// LDS bytes: [0,16K) A buf0; [16K,32K) A buf1 / fill scratch raw[64][64]f32 / norms;
//            [32K,96K) B hi [16 cc][64 r][32 c] bf16; [96K,160K) B lo.
// 512 thr = 8 waves (4 kg x 2 pg), 2 waves/SIMD. Steps: kt 0..3 (256 codes) x cc 0..15
// (32 c); hi+lo MFMA accumulate into the same acc. A chunk 256k x 32c dbuf 2x16KB.
__global__ __launch_bounds__(512, 1) void k_gemm(const uint16_t* __restrict__ cbb,
                                                 const float* __restrict__ x,
                                                 int* __restrict__ idx,
                                                 int* __restrict__ counts) {
  extern __shared__ uint8_t smem[];
  uint16_t* lds = (uint16_t*)smem;

  const int tid = threadIdx.x;
  const int lane = tid & 63, wid = tid >> 6;
  const int kg = wid >> 1, pg = wid & 1;
  const int g = lane >> 4, r15 = lane & 15;
  const int blk = blockIdx.x;  // 512
  const int n0 = blk << 6;
  const int b = blk >> 4, p0 = (blk & 15) << 6;

  // stage A chunk (kt,cc): 256 k-rows x 32 c, linear LDS [row][4x16B]
  auto stageA = [&](int buf, int kt, int cc) {
    uint16_t* dst = lds + (buf << 13);
    const uint16_t* srcb = cbb + ((size_t)(kt << 8)) * 512 + (cc << 5);
#pragma unroll
    for (int i = 0; i < 2; ++i) {
      int u = (i << 9) + tid;
      gl_lds16(srcb + (size_t)(u >> 2) * 512 + ((u & 3) << 3), dst + (u << 3));
    }
  };
  stageA(0, 0, 0);  // prefetch overlaps the whole fill phase

  // ---- fill: x -> soft_sign -> split bf16 into resident B, + f64 row norms ----
  float* raw = (float*)(smem + 16384);  // [64][64], XOR-swizzled p-blocks
  const float* xb = x + (((size_t)b) << 19) + p0;
  const int fr = tid >> 3, foc = tid & 7;  // row 0..63, octet 0..7
  double nsum = 0.0;
  for (int ch = 0; ch < 8; ++ch) {
    int c0 = ch << 6;
#pragma unroll
    for (int it = 0; it < 2; ++it) {
      int u = (it << 9) + tid;
      int cr = u >> 4, q = u & 15;
      const float4 v =
          *reinterpret_cast<const float4*>(xb + (size_t)(c0 + cr) * 1024 + (q << 2));
      *reinterpret_cast<float4*>(raw + (cr << 6) +
                                 ((q << 2) ^ ((((cr >> 3) & 7)) << 2))) = v;
    }
    __syncthreads();
    short8_t h8, l8;
    double ls = 0.0;
#pragma unroll
    for (int j = 0; j < 8; ++j) {
      int c = (foc << 3) + j;
      float xs = soft_sign(raw[(c << 6) + (fr ^ (foc << 2))]);
      uint16_t h = f2bf(xs);
      uint16_t l = f2bf(xs - bf2f(h));
      h8[j] = (short)h;
      l8[j] = (short)l;
      float sq = xs * xs;
      ls += (double)sq;
    }
    nsum += ls;
    int cc = (ch << 1) + (foc >> 2), jj = foc & 3;
    uint16_t* bwp = (uint16_t*)(smem + 32768 + (cc << 12)) + (fr << 5) + (jj << 3);
    *reinterpret_cast<short8_t*>(bwp) = h8;
    *reinterpret_cast<short8_t*>(bwp + 32768) = l8;  // lo at +64KB
    __syncthreads();
  }
  // norms: reduce over octets (deterministic), park in scratch, read s_p
  {
    double s = nsum;
    s += __shfl_xor(s, 1);
    s += __shfl_xor(s, 2);
    s += __shfl_xor(s, 4);
    if (foc == 0) ((float*)raw)[fr] = (float)s + 512.0f;
  }
  __syncthreads();
  float s_p[2];
#pragma unroll
  for (int ac = 0; ac < 2; ++ac) s_p[ac] = ((float*)raw)[(pg << 5) + (ac << 4) + r15];
  __syncthreads();  // s_p reads done before step 0 stages into buf1

  float best_d[2];
  int best_k[2];
#pragma unroll
  for (int ac = 0; ac < 2; ++ac) { best_d[ac] = 3.4e38f; best_k[ac] = 0; }

  f32x4_t acc[4][2];
  int cur = 0;
  for (int step = 0; step < 64; ++step) {
    int kt = step >> 4, cc = step & 15;
    if (cc == 0) {
#pragma unroll
      for (int i = 0; i < 4; ++i)
#pragma unroll
        for (int j = 0; j < 2; ++j) acc[i][j] = (f32x4_t){0.f, 0.f, 0.f, 0.f};
    }
    if (step < 63) {
      int ns = step + 1;
      stageA(cur ^ 1, ns >> 4, ns & 15);
    }

    const uint16_t* A = lds + (cur << 13);
    const uint16_t* Bh = (uint16_t*)(smem + 32768) + (cc << 11);
    bf16x8_t af[4], fbh[2], fbl[2];
#pragma unroll
    for (int ar = 0; ar < 4; ++ar) {
      int row = (kg << 6) + (ar << 4) + r15;
      af[ar] = __builtin_bit_cast(bf16x8_t,
                                  *(const short8_t*)(A + (row << 5) + (g << 3)));
    }
#pragma unroll
    for (int ac = 0; ac < 2; ++ac) {
      int row = (pg << 5) + (ac << 4) + r15;
      fbh[ac] = __builtin_bit_cast(bf16x8_t,
                                   *(const short8_t*)(Bh + (row << 5) + (g << 3)));
      fbl[ac] = __builtin_bit_cast(
          bf16x8_t, *(const short8_t*)(Bh + 32768 + (row << 5) + (g << 3)));
    }
#pragma unroll
    for (int ar = 0; ar < 4; ++ar)
#pragma unroll
      for (int ac = 0; ac < 2; ++ac) {
        acc[ar][ac] =
            __builtin_amdgcn_mfma_f32_16x16x32_bf16(af[ar], fbh[ac], acc[ar][ac], 0, 0, 0);
        acc[ar][ac] =
            __builtin_amdgcn_mfma_f32_16x16x32_bf16(af[ar], fbl[ac], acc[ar][ac], 0, 0, 0);
      }

    if (cc == 15) {  // fold 256-code tile into running argmin
      int kbase = (kt << 8) + (kg << 6);
#pragma unroll
      for (int ar = 0; ar < 4; ++ar)
#pragma unroll
        for (int ac = 0; ac < 2; ++ac)
#pragma unroll
          for (int rg = 0; rg < 4; ++rg) {
            float d = fmaf(-2.0f, acc[ar][ac][rg], s_p[ac]);  // fl(s - 2*dot)
            int kk = kbase + (ar << 4) + (g << 2) + rg;
            bool better = (d < best_d[ac]) || (d == best_d[ac] && kk < best_k[ac]);
            if (better) { best_d[ac] = d; best_k[ac] = kk; }
          }
    }

    asm volatile("s_waitcnt vmcnt(0)" ::: "memory");
    __builtin_amdgcn_s_barrier();
    asm volatile("" ::: "memory");
    cur ^= 1;
  }

  // merge g-groups (lex order: min d, then min k)
  float rd0, rd1;
  int rk0, rk1;
  {
    float d = best_d[0];
    int k = best_k[0];
#pragma unroll
    for (int m = 16; m <= 32; m <<= 1) {
      float od = __shfl_xor(d, m);
      int ok = __shfl_xor(k, m);
      if (od < d || (od == d && ok < k)) { d = od; k = ok; }
    }
    rd0 = d; rk0 = k;
  }
  {
    float d = best_d[1];
    int k = best_k[1];
#pragma unroll
    for (int m = 16; m <= 32; m <<= 1) {
      float od = __shfl_xor(d, m);
      int ok = __shfl_xor(k, m);
      if (od < d || (od == d && ok < k)) { d = od; k = ok; }
    }
    rd1 = d; rk1 = k;
  }
  float* sd = (float*)smem;
  int* sk = (int*)(smem + 1024);
  __syncthreads();
  if (g < 2) {
    float dv = (g == 0) ? rd0 : rd1;
    int kv = (g == 0) ? rk0 : rk1;
    sd[(kg << 6) + (pg << 5) + (g << 4) + r15] = dv;
    sk[(kg << 6) + (pg << 5) + (g << 4) + r15] = kv;
  }
  __syncthreads();
  if (tid < 64) {
    float d0 = sd[tid];
    int k0 = sk[tid];
#pragma unroll
    for (int kgi = 1; kgi < 4; ++kgi) {
      float d1 = sd[(kgi << 6) + tid];
      int k1 = sk[(kgi << 6) + tid];
      if (d1 < d0 || (d1 == d0 && k1 < k0)) { d0 = d1; k0 = k1; }
    }
    idx[n0 + tid] = k0;
    atomicAdd(&counts[k0], 1);
  }
}

// ---------------- perplexity scalars ----------------
__global__ __launch_bounds__(256) void k_perp(const int* __restrict__ counts,
                                              float* __restrict__ out2) {
  int tid = threadIdx.x;
  float local = 0.0f;
  for (int i = tid; i < KC; i += 256) {
    int c = counts[i];
    if (c > 0) {
      float p = (float)c * (1.0f / 32768.0f);
      local += p * logf(p);
    }
  }
#pragma unroll
  for (int m = 1; m < 64; m <<= 1) local += __shfl_xor(local, m);
  __shared__ float wsum[4];
  if ((tid & 63) == 0) wsum[tid >> 6] = local;
  __syncthreads();
  if (tid == 0) {
    float entropy = -(wsum[0] + wsum[1] + wsum[2] + wsum[3]);
    float pl = 1.0f / expf(entropy);
    out2[0] = pl;
    out2[1] = 0.25f * pl;
  }
}

// ---------------- gather via bit-packed codebook in LDS ----------------
__global__ __launch_bounds__(256) void k_gather(const int* __restrict__ idx,
                                                const uint32_t* __restrict__ pack,
                                                float* __restrict__ out) {
  __shared__ uint32_t lp[16384];  // 64 KB sign table
  int tid = threadIdx.x;
#pragma unroll
  for (int i = 0; i < 16; ++i)
    reinterpret_cast<uint4*>(lp)[i * 256 + tid] =
        reinterpret_cast<const uint4*>(pack)[i * 256 + tid];
  __syncthreads();
  int base = blockIdx.x * 2048;  // grid 2048
  for (int it = 0; it < 8; ++it) {
    int t = base + it * 256 + tid;
    int pq = t & 255;
    int c = (t >> 8) & 511;
    int b = t >> 17;
    int4 iv = reinterpret_cast<const int4*>(idx)[(b << 8) + pq];
    int cw = c >> 5, cbit = c & 31;
    float4 r;
    r.x = ((lp[(cw << 10) + iv.x] >> cbit) & 1) ? 1.0f : -1.0f;
    r.y = ((lp[(cw << 10) + iv.y] >> cbit) & 1) ? 1.0f : -1.0f;
    r.z = ((lp[(cw << 10) + iv.z] >> cbit) & 1) ? 1.0f : -1.0f;
    r.w = ((lp[(cw << 10) + iv.w] >> cbit) & 1) ? 1.0f : -1.0f;
    reinterpret_cast<float4*>(out)[t] = r;
  }
}

extern "C" void kernel_launch(void* const* d_in, const int* in_sizes, int n_in,
                              void* d_out, int out_size, void* d_ws, size_t ws_size,
                              hipStream_t stream) {
  (void)in_sizes; (void)n_in; (void)out_size; (void)ws_size;
  const float* x = (const float*)d_in[0];
  const float* cb = (const float*)d_in[1];
  float* out = (float*)d_out;

  uint8_t* ws = (uint8_t*)d_ws;
  uint16_t* cbb = (uint16_t*)ws;                         // 1 MB
  int* idx = (int*)(ws + 1048576);                       // 128 KB
  int* counts = (int*)(ws + 1048576 + 131072);           // 4 KB
  uint32_t* pack = (uint32_t*)(ws + 1048576 + 131072 + 4096);  // 64 KB

  hipFuncSetAttribute((const void*)k_gemm, hipFuncAttributeMaxDynamicSharedMemorySize,
                      163840);

  k_cb<<<2048, 256, 0, stream>>>(cb, cbb, pack);
  hipMemsetAsync(counts, 0, 4096, stream);
  k_gemm<<<512, 512, 163840, stream>>>(cbb, x, idx, counts);
  k_perp<<<1, 256, 0, stream>>>(counts, out + 16777216);
  k_gather<<<2048, 256, 0, stream>>>(idx, pack, out);
}